// Round 4
// baseline (302.404 us; speedup 1.0000x reference)
//
#include <hip/hip_runtime.h>
#include <hip/hip_bf16.h>

typedef __attribute__((ext_vector_type(8))) short bf16x8;
typedef __attribute__((ext_vector_type(4))) float f32x4;

#define NB 16384
#define NE 31

static __device__ __forceinline__ unsigned short f2b(float f) {
  unsigned int u = __builtin_bit_cast(unsigned int, f);
  return (unsigned short)((u + 0x7fffu + ((u >> 16) & 1u)) >> 16);
}
static __device__ __forceinline__ float b2f(unsigned short h) {
  return __builtin_bit_cast(float, ((unsigned int)h) << 16);
}

// ---------------------------------------------------------------------------
// k0_all: all weight preprocessing in one launch.
// W1 (bf16 [1792][256]):
//   rows 0..255    = 0.125*Wq
//   rows 256..511  = Wk
//   rows 512..767  = Wv
//   rows 768..1791 = Wqo[h*256+c][k] = sum_d 0.125*Wq[h*64+d][k]*Wok[h*64+d][c]
// W2 (bf16 [256][1280]): row n: cols h*256+c = sum_d Wov[h*64+d][c]*Wc[n][h*64+d];
//                        cols 1024+m = Wc[n][m]
// ---------------------------------------------------------------------------
__global__ void k0_all(const float* __restrict__ wq, const float* __restrict__ wk,
                       const float* __restrict__ wv, const float* __restrict__ wok,
                       const float* __restrict__ wov, const float* __restrict__ wc,
                       unsigned short* __restrict__ W1, unsigned short* __restrict__ W2) {
  int r = blockIdx.x, k = threadIdx.x;
  if (r < 1024) {
    if (r < 256) {
      W1[r * 256 + k] = f2b(0.125f * wq[r * 256 + k]);
    } else if (r < 512) {
      W1[r * 256 + k] = f2b(wk[(r - 256) * 256 + k]);
    } else if (r < 768) {
      W1[r * 256 + k] = f2b(wv[(r - 512) * 256 + k]);
    } else {
      int n = r - 768;
      W2[n * 1280 + 1024 + k] = f2b(wc[n * 256 + k]);
    }
  } else if (r < 2048) {
    int m = r - 1024;  // 0..1023
    int h = m >> 8, c = m & 255;
    float acc = 0.f;
#pragma unroll 8
    for (int d = 0; d < 64; ++d)
      acc = fmaf(wq[(h * 64 + d) * 256 + k], wok[(h * 64 + d) * 256 + c], acc);
    W1[(768 + m) * 256 + k] = f2b(0.125f * acc);
  } else {
    int n = r - 2048;  // 0..255
#pragma unroll 1
    for (int mi = 0; mi < 4; ++mi) {
      float acc = 0.f;
#pragma unroll 8
      for (int d = 0; d < 64; ++d)
        acc = fmaf(wov[(mi * 64 + d) * 256 + k], wc[n * 256 + mi * 64 + d], acc);
      W2[n * 1280 + mi * 256 + k] = f2b(acc);
    }
  }
}

// ---------------------------------------------------------------------------
// k1b: qkv2[b][n] = sum_k ego[b][k] * W1[n][k], n in [0,1792). bf16 out.
// 512 blocks x 32 rows (2 blocks/CU); 4 waves, each a 448-col stripe.
// ---------------------------------------------------------------------------
__global__ __launch_bounds__(256, 2)
void k1b(const float* __restrict__ ego, const unsigned short* __restrict__ W1,
         unsigned short* __restrict__ qkv2) {
  __shared__ __align__(16) unsigned short Al[32 * 256];  // 16KB, swizzled
  const int tid = threadIdx.x;
  const int bM = blockIdx.x * 32;
#pragma unroll
  for (int it = 0; it < 4; ++it) {
    int c = tid + it * 256;                // 1024 chunks of 8 f32
    int row = c >> 5, k8 = c & 31;
    const float4* g = (const float4*)(ego + (size_t)(bM + row) * 256 + k8 * 8);
    float4 x = g[0], y = g[1];
    float t[8] = {x.x, x.y, x.z, x.w, y.x, y.y, y.z, y.w};
    bf16x8 v;
#pragma unroll
    for (int j = 0; j < 8; ++j) v[j] = (short)f2b(t[j]);
    int byteoff = row * 512 + ((k8 * 16) ^ ((row & 7) << 4));
    *(bf16x8*)((char*)Al + byteoff) = v;
  }
  __syncthreads();
  const int w = tid >> 6, lane = tid & 63, lr = lane & 15, lkg = lane >> 4;
#pragma unroll 1
  for (int cb = 0; cb < 7; ++cb) {
    int bN = w * 448 + cb * 64;
    f32x4 acc[2][4];
#pragma unroll
    for (int mt = 0; mt < 2; ++mt)
#pragma unroll
      for (int nt = 0; nt < 4; ++nt) acc[mt][nt] = (f32x4){0.f, 0.f, 0.f, 0.f};
#pragma unroll
    for (int kk = 0; kk < 8; ++kk) {
      int kidx = kk * 32 + lkg * 8;
      bf16x8 bfr[4];
#pragma unroll
      for (int nt = 0; nt < 4; ++nt)
        bfr[nt] = *(const bf16x8*)(W1 + (size_t)(bN + nt * 16 + lr) * 256 + kidx);
#pragma unroll
      for (int mt = 0; mt < 2; ++mt) {
        int row = mt * 16 + lr;
        int byteoff = row * 512 + ((kidx * 2) ^ ((row & 7) << 4));
        bf16x8 a = *(const bf16x8*)((const char*)Al + byteoff);
#pragma unroll
        for (int nt = 0; nt < 4; ++nt)
          acc[mt][nt] = __builtin_amdgcn_mfma_f32_16x16x32_bf16(a, bfr[nt], acc[mt][nt], 0, 0, 0);
      }
    }
#pragma unroll
    for (int mt = 0; mt < 2; ++mt)
#pragma unroll
      for (int nt = 0; nt < 4; ++nt)
#pragma unroll
        for (int j = 0; j < 4; ++j) {
          int row = bM + mt * 16 + lkg * 4 + j;
          int col = bN + nt * 16 + lr;
          qkv2[(size_t)row * 1792 + col] = f2b(acc[mt][nt][j]);
        }
  }
}

// ---------------------------------------------------------------------------
// ks_attn: per item. Xr = swizzled bf16 [32][256] (row 31 zero).
// scores via MFMA (Qo . x), s0 via VALU, masked softmax, ctx = sum_e p x_e.
// u[b][1280] = [ctx_0..ctx_3 ; p0*v_ego]; attn probs to d_out.
// ---------------------------------------------------------------------------
__global__ __launch_bounds__(256, 6)
void ks_attn(const float* __restrict__ others, const int* __restrict__ mask,
             const unsigned short* __restrict__ qkv2,
             unsigned short* __restrict__ u,
             float* __restrict__ attnout) {
  __shared__ __align__(16) unsigned short Xr[32 * 256];   // 16KB, XOR-swizzled
  __shared__ __align__(16) unsigned short Qo_l[1024];     // 4 heads x 256
  __shared__ __align__(16) unsigned short qk_l[768];      // q,k,v ego (q pre-scaled)
  __shared__ float sco_l[4][32];
  __shared__ float Pl[4][32];
  const int tid = threadIdx.x;
  const size_t b = blockIdx.x;

  // ---- stage X (bf16, swizzled) + qkv2 row ----
  {
    int e = tid >> 3, c = tid & 7;  // 8 threads per row, 32 floats each
    if (e < 31) {
      const float4* src = (const float4*)(others) + ((b * 31 + e) * 64 + c * 8);
#pragma unroll
      for (int h = 0; h < 2; ++h) {
        float4 f[4];
#pragma unroll
        for (int j = 0; j < 4; ++j) f[j] = src[h * 4 + j];
#pragma unroll
        for (int j = 0; j < 2; ++j) {
          bf16x8 v;
          v[0] = (short)f2b(f[2 * j].x);     v[1] = (short)f2b(f[2 * j].y);
          v[2] = (short)f2b(f[2 * j].z);     v[3] = (short)f2b(f[2 * j].w);
          v[4] = (short)f2b(f[2 * j + 1].x); v[5] = (short)f2b(f[2 * j + 1].y);
          v[6] = (short)f2b(f[2 * j + 1].z); v[7] = (short)f2b(f[2 * j + 1].w);
          int byteoff = e * 512 + ((c * 64 + h * 32 + j * 16) ^ ((e & 7) << 4));
          *(bf16x8*)((char*)Xr + byteoff) = v;
        }
      }
    } else {
      bf16x8 z = (bf16x8){0, 0, 0, 0, 0, 0, 0, 0};
#pragma unroll
      for (int q4 = 0; q4 < 4; ++q4) {
        int byteoff = 31 * 512 + ((c * 64 + q4 * 16) ^ ((31 & 7) << 4));
        *(bf16x8*)((char*)Xr + byteoff) = z;
      }
    }
    if (tid < 224) {
      bf16x8 v = *(const bf16x8*)(qkv2 + b * 1792 + tid * 8);
      if (tid < 96) *(bf16x8*)(&qk_l[tid * 8]) = v;
      else          *(bf16x8*)(&Qo_l[(tid - 96) * 8]) = v;
    }
  }
  __syncthreads();

  const int w = tid >> 6, lane = tid & 63, lr = lane & 15, lkg = lane >> 4;

  // ---- scores ----
  if (w < 2) {
    // S[m][n] = Qo[m] . x_n; wave w covers entities n = w*16 .. w*16+15
    f32x4 acc = (f32x4){0.f, 0.f, 0.f, 0.f};
#pragma unroll
    for (int kk = 0; kk < 8; ++kk) {
      bf16x8 a = *(const bf16x8*)(&Qo_l[(lr & 3) * 256 + kk * 32 + lkg * 8]);
      int row = w * 16 + lr;
      int byteoff = row * 512 + ((kk * 64 + lkg * 16) ^ ((row & 7) << 4));
      bf16x8 bb = *(const bf16x8*)((const char*)Xr + byteoff);
      acc = __builtin_amdgcn_mfma_f32_16x16x32_bf16(a, bb, acc, 0, 0, 0);
    }
    if (lkg == 0) {
      int n = w * 16 + lr;
      if (n < NE) {
#pragma unroll
        for (int j = 0; j < 4; ++j) sco_l[j][1 + n] = acc[j];
      }
    }
  } else if (w == 2) {
    // s0[h] = q_h . k_ego_h (q pre-scaled)
    int h = lane >> 4, i = lane & 15;
    const unsigned short* q4 = &qk_l[h * 64 + i * 4];
    const unsigned short* k4p = &qk_l[256 + h * 64 + i * 4];
    float s = 0.f;
#pragma unroll
    for (int j = 0; j < 4; ++j) s += b2f(q4[j]) * b2f(k4p[j]);
#pragma unroll
    for (int off = 1; off < 16; off <<= 1) s += __shfl_xor(s, off, 16);
    if (i == 0) sco_l[h][0] = s;
  }
  __syncthreads();

  // ---- masked softmax: wave w = head w (lanes 32..63 duplicate) ----
  {
    int key = lane & 31;
    float s = sco_l[w][key];
    if (mask[b * 32 + key] != 0) s = -1e9f;
    float mx = s;
#pragma unroll
    for (int off = 1; off < 32; off <<= 1) mx = fmaxf(mx, __shfl_xor(mx, off, 32));
    float ex = __expf(s - mx);
    float sm = ex;
#pragma unroll
    for (int off = 1; off < 32; off <<= 1) sm += __shfl_xor(sm, off, 32);
    float p = ex / sm;
    if (lane < 32) {
      Pl[w][key] = p;
      attnout[b * 128 + w * 32 + key] = p;
    }
  }
  // (no barrier: wave w only consumes Pl[w], which it wrote itself)

  // ---- ctx_h = sum_e p_e x_e ; u = [ctx ; p0*v_ego] ----
  {
    float a0 = 0.f, a1 = 0.f, a2 = 0.f, a3 = 0.f;
#pragma unroll
    for (int e = 0; e < NE; ++e) {
      float p = Pl[w][1 + e];
      int byteoff = e * 512 + ((lane * 8) ^ ((e & 7) << 4));
      ushort4 xv = *(const ushort4*)((const char*)Xr + byteoff);
      a0 = fmaf(p, b2f(xv.x), a0);
      a1 = fmaf(p, b2f(xv.y), a1);
      a2 = fmaf(p, b2f(xv.z), a2);
      a3 = fmaf(p, b2f(xv.w), a3);
    }
    ushort4 st;
    st.x = f2b(a0); st.y = f2b(a1); st.z = f2b(a2); st.w = f2b(a3);
    *(ushort4*)(u + b * 1280 + w * 256 + lane * 4) = st;
    float p0 = Pl[w][0];
    u[b * 1280 + 1024 + w * 64 + lane] = f2b(p0 * b2f(qk_l[512 + w * 64 + lane]));
  }
}

// ---------------------------------------------------------------------------
// k4: res[b][n] = (sum_m u[b][m]*W2[n][m] + ego[b][n]) * 0.5
// 512 blocks x 32 rows; K looped in 5 chunks of 256; 4 waves = 64-col stripes.
// ---------------------------------------------------------------------------
__global__ __launch_bounds__(256, 2)
void k4_out(const unsigned short* __restrict__ u, const unsigned short* __restrict__ W2,
            const float* __restrict__ ego, float* __restrict__ out) {
  __shared__ __align__(16) unsigned short Au[32 * 256];  // 16KB, swizzled
  const int tid = threadIdx.x;
  const int bM = blockIdx.x * 32;
  const int w = tid >> 6, lane = tid & 63, lr = lane & 15, lkg = lane >> 4;
  f32x4 acc[2][4];
#pragma unroll
  for (int mt = 0; mt < 2; ++mt)
#pragma unroll
    for (int nt = 0; nt < 4; ++nt) acc[mt][nt] = (f32x4){0.f, 0.f, 0.f, 0.f};
#pragma unroll 1
  for (int kc = 0; kc < 5; ++kc) {
#pragma unroll
    for (int it = 0; it < 4; ++it) {
      int c = tid + it * 256;              // 1024 chunks of 8 bf16
      int row = c >> 5, k8 = c & 31;
      bf16x8 v = *(const bf16x8*)(u + (size_t)(bM + row) * 1280 + kc * 256 + k8 * 8);
      int byteoff = row * 512 + ((k8 * 16) ^ ((row & 7) << 4));
      *(bf16x8*)((char*)Au + byteoff) = v;
    }
    __syncthreads();
#pragma unroll
    for (int kk = 0; kk < 8; ++kk) {
      int kidx = kk * 32 + lkg * 8;
      bf16x8 bfr[4];
#pragma unroll
      for (int nt = 0; nt < 4; ++nt)
        bfr[nt] = *(const bf16x8*)(W2 + (size_t)(w * 64 + nt * 16 + lr) * 1280 + kc * 256 + kidx);
#pragma unroll
      for (int mt = 0; mt < 2; ++mt) {
        int row = mt * 16 + lr;
        int byteoff = row * 512 + ((kidx * 2) ^ ((row & 7) << 4));
        bf16x8 a = *(const bf16x8*)((const char*)Au + byteoff);
#pragma unroll
        for (int nt = 0; nt < 4; ++nt)
          acc[mt][nt] = __builtin_amdgcn_mfma_f32_16x16x32_bf16(a, bfr[nt], acc[mt][nt], 0, 0, 0);
      }
    }
    __syncthreads();
  }
#pragma unroll
  for (int mt = 0; mt < 2; ++mt)
#pragma unroll
    for (int nt = 0; nt < 4; ++nt)
#pragma unroll
      for (int j = 0; j < 4; ++j) {
        int row = bM + mt * 16 + lkg * 4 + j;
        int col = w * 64 + nt * 16 + lr;
        out[(size_t)row * 256 + col] = (acc[mt][nt][j] + ego[(size_t)row * 256 + col]) * 0.5f;
      }
}

extern "C" void kernel_launch(void* const* d_in, const int* in_sizes, int n_in,
                              void* d_out, int out_size, void* d_ws, size_t ws_size,
                              hipStream_t stream) {
  const float* ego    = (const float*)d_in[0];
  const float* others = (const float*)d_in[1];
  const int*   mask   = (const int*)d_in[2];
  const float* wq  = (const float*)d_in[3];
  const float* wk  = (const float*)d_in[4];
  const float* wv  = (const float*)d_in[5];
  const float* wok = (const float*)d_in[6];
  const float* wov = (const float*)d_in[7];
  const float* wc  = (const float*)d_in[8];

  unsigned short* W1   = (unsigned short*)d_ws;                 // 1792*256
  unsigned short* W2   = W1 + 1792 * 256;                       // 256*1280
  unsigned short* qkv2 = W2 + 256 * 1280;                       // NB*1792
  unsigned short* u    = qkv2 + (size_t)NB * 1792;              // NB*1280

  float* res  = (float*)d_out;                                  // NB*256 f32
  float* attn = res + (size_t)NB * 256;                         // NB*128 f32

  hipLaunchKernelGGL(k0_all, dim3(2304), dim3(256), 0, stream,
                     wq, wk, wv, wok, wov, wc, W1, W2);
  hipLaunchKernelGGL(k1b,    dim3(512),  dim3(256), 0, stream, ego, W1, qkv2);
  hipLaunchKernelGGL(ks_attn, dim3(NB),  dim3(256), 0, stream, others, mask, qkv2, u, attn);
  hipLaunchKernelGGL(k4_out, dim3(512),  dim3(256), 0, stream, u, W2, ego, res);
}